// Round 15
// baseline (4018.814 us; speedup 1.0000x reference)
//
#include <hip/hip_runtime.h>

#define TT 512
#define BB 256
#define HH 512
#define DD 105
#define RS 85
#define NRULE 20
#define NOUT 33
#define HALF 256

#define NFRAG_REC 512              // 32 mtiles x 16 ktiles
#define NFRAG_IN  128              // 32 mtiles x 4 ktiles (k padded 105->128)
#define NFRAG_OUT 48               // 3 mtiles (o padded 33->48) x 16 ktiles
#define FRAG_IN_OFF  (NFRAG_REC)
#define FRAG_OUT_OFF (NFRAG_REC + NFRAG_IN)
#define NFRAG_TOT (NFRAG_REC + NFRAG_IN + NFRAG_OUT)

#define WP_BYTES    ((size_t)NFRAG_TOT * 1024)         // 704512

// ---- fallback (R7) layout ----
#define PREC_OFF    WP_BYTES
#define PREC_STRIDE ((size_t)32768)
#define POUT_OFF    (PREC_OFF + 32 * PREC_STRIDE)
#define POUT_STRIDE ((size_t)9216)
#define EXCH_BYTES  (32 * PREC_STRIDE + 16 * POUT_STRIDE)

// ---- big-path layout: wp | pre/hidden (aliased, fragment-linear) ----
// pre element (t, g, ctid in [0,1024), slot s in [0,8)) at short offset
//   ((t*16+g)*1024 + ctid)*8 + s
// holds value for b = ctid&15,
//   h = ((ctid>>6)*2 + (s>>2))*16 + ((ctid>>4)&3)*4 + (s&3)
#define BPRE_OFF    WP_BYTES
#define BPRE_BYTES  ((size_t)TT * 16 * 16 * 512 * 2)   // 134217728
#define SNEED       (BPRE_OFF + BPRE_BYTES)            // 134922240

#define RETRY_GUARD 100000

typedef __bf16 bf16x8 __attribute__((ext_vector_type(8)));
typedef float  f32x4  __attribute__((ext_vector_type(4)));
typedef unsigned long long u64;
typedef unsigned short us;

__device__ __forceinline__ us f2bf(float f) {
  unsigned u = __builtin_bit_cast(unsigned, f);
  u += 0x7FFFu + ((u >> 16) & 1u);            // RNE
  return (us)(u >> 16);
}
__device__ __forceinline__ float bf2f(us v) {
  return __builtin_bit_cast(float, (unsigned)v << 16);
}
__device__ __forceinline__ u64 ld_agent(const u64* p) {
  return __hip_atomic_load(p, __ATOMIC_RELAXED, __HIP_MEMORY_SCOPE_AGENT);
}
__device__ __forceinline__ void st_agent(u64* p, u64 v) {
  __hip_atomic_store(p, v, __ATOMIC_RELAXED, __HIP_MEMORY_SCOPE_AGENT);
}
__device__ __forceinline__ float bfhi(unsigned w) {
  return __builtin_bit_cast(float, w & 0xffff0000u);
}
__device__ __forceinline__ unsigned pkv(float v, unsigned tag) {
  return ((unsigned)f2bf(v) << 16) | tag;
}
__device__ __forceinline__ int tags4_ok(u64 v0, u64 v1, u64 v2, u64 v3, unsigned tag) {
  return (((unsigned)v0 & 0xffffu) == tag) & (((unsigned)(v0 >> 32) & 0xffffu) == tag)
       & (((unsigned)v1 & 0xffffu) == tag) & (((unsigned)(v1 >> 32) & 0xffffu) == tag)
       & (((unsigned)v2 & 0xffffu) == tag) & (((unsigned)(v2 >> 32) & 0xffffu) == tag)
       & (((unsigned)v3 & 0xffffu) == tag) & (((unsigned)(v3 >> 32) & 0xffffu) == tag);
}
__device__ __forceinline__ int tags2_ok(u64 v0, u64 v1, unsigned tag) {
  return (((unsigned)v0 & 0xffffu) == tag) & (((unsigned)(v0 >> 32) & 0xffffu) == tag)
       & (((unsigned)v1 & 0xffffu) == tag) & (((unsigned)(v1 >> 32) & 0xffffu) == tag);
}

// Pack Wrec*mask, [Ws|Wr] (k padded to 128), Wout (m padded to 48) into MFMA
// 16x16x32 A-frag layout: frag f, lane l holds M[mt*16+(l&15)][kt*32+(l>>4)*8+j]
__global__ void pack_weights(const float* __restrict__ Ws_w, const float* __restrict__ Wr_w,
                             const float* __restrict__ Wrec_w, const float* __restrict__ mask,
                             const float* __restrict__ Wout_w, us* __restrict__ wp)
{
  int gid = blockIdx.x * blockDim.x + threadIdx.x;
  if (gid >= NFRAG_TOT * 64) return;
  int f = gid >> 6, lane = gid & 63;
  int m16 = lane & 15, kg = lane >> 4;
  float v[8];
  if (f < NFRAG_REC) {
    int mt = f >> 4, kt = f & 15;
    int m = mt * 16 + m16, k0 = kt * 32 + kg * 8;
#pragma unroll
    for (int j = 0; j < 8; ++j) {
      int k = k0 + j;
      v[j] = Wrec_w[m * HH + k] * mask[m * HH + k];
    }
  } else if (f < FRAG_OUT_OFF) {
    int ff = f - FRAG_IN_OFF;
    int mt = ff >> 2, kt = ff & 3;
    int m = mt * 16 + m16, k0 = kt * 32 + kg * 8;
#pragma unroll
    for (int j = 0; j < 8; ++j) {
      int k = k0 + j;
      float val = 0.f;
      if (k < RS) val = Ws_w[m * RS + k];
      else if (k < DD) val = Wr_w[m * NRULE + (k - RS)];
      v[j] = val;
    }
  } else {
    int ff = f - FRAG_OUT_OFF;
    int mt = ff >> 4, kt = ff & 15;
    int m = mt * 16 + m16, k0 = kt * 32 + kg * 8;
#pragma unroll
    for (int j = 0; j < 8; ++j) {
      int k = k0 + j;
      v[j] = (m < NOUT) ? Wout_w[m * HH + k] : 0.f;
    }
  }
  unsigned o[4];
#pragma unroll
  for (int j = 0; j < 4; ++j)
    o[j] = (unsigned)f2bf(v[2 * j]) | ((unsigned)f2bf(v[2 * j + 1]) << 16);
  uint4 st = make_uint4(o[0], o[1], o[2], o[3]);
  *reinterpret_cast<uint4*>(wp + (size_t)f * 512 + lane * 8) = st;
}

// ============================ BIG PATH ====================================
// pre (fragment-linear for the 1024-thread seq consumer)
__global__ __launch_bounds__(512)
void precompute_pre(const float* __restrict__ x, const float* __restrict__ noise,
                    const float* __restrict__ Ws_b, const float* __restrict__ Wrec_b,
                    const us* __restrict__ wp, us* __restrict__ pre)
{
  __shared__ alignas(16) us x_lds[16 * 128];
  const int t  = blockIdx.x >> 4;
  const int gg = blockIdx.x & 15;
  const int gb = gg * 16;
  const int tid = threadIdx.x;
  const int wv = tid >> 6, lane = tid & 63;
  const int bcol = lane & 15, krow = lane >> 4;
  const int sw = (bcol & 7) << 3;
  const uint4* wp4 = reinterpret_cast<const uint4*>(wp);

  for (int i = tid; i < 16 * 128; i += 512) x_lds[i] = 0;
  __syncthreads();
  if (tid < 420) {
    f32x4 xv = reinterpret_cast<const f32x4*>(x + ((size_t)t * BB + gb) * DD)[tid];
#pragma unroll
    for (int j = 0; j < 4; ++j) {
      int e = tid * 4 + j;
      int b = e / DD, k = e - b * DD;
      x_lds[b * 128 + (k ^ ((b & 7) << 3))] = f2bf(xv[j]);
    }
  }
  __syncthreads();

#pragma unroll
  for (int jj = 0; jj < 4; ++jj) {
    int m = wv * 4 + jj;                         // 0..31
    f32x4 acc = {0.f, 0.f, 0.f, 0.f};
#pragma unroll
    for (int kx = 0; kx < 4; ++kx) {
      int k0 = kx * 32 + krow * 8;
      bf16x8 xb = __builtin_bit_cast(bf16x8,
          *reinterpret_cast<const uint4*>(&x_lds[bcol * 128 + (k0 ^ sw)]));
      bf16x8 aw = __builtin_bit_cast(bf16x8, wp4[(FRAG_IN_OFF + m * 4 + kx) * 64 + lane]);
      acc = __builtin_amdgcn_mfma_f32_16x16x32_bf16(aw, xb, acc, 0, 0, 0);
    }
    int h0 = m * 16 + krow * 4;
    f32x4 b1 = *reinterpret_cast<const f32x4*>(Ws_b + h0);
    f32x4 b2 = *reinterpret_cast<const f32x4*>(Wrec_b + h0);
    f32x4 nz = *reinterpret_cast<const f32x4*>(noise + ((size_t)t * BB + gb + bcol) * HH + h0);
    us ov[4];
#pragma unroll
    for (int r = 0; r < 4; ++r)
      ov[r] = f2bf(acc[r] + b1[r] + b2[r] + 0.05f * nz[r]);
    // consumer thread ctid = (m>>1)*64 + krow*16 + bcol, slot base (m&1)*4
    int ctid = (m >> 1) * 64 + krow * 16 + bcol;
    us* dst = pre + (((size_t)t * 16 + gg) * 1024 + ctid) * 8 + (m & 1) * 4;
    *reinterpret_cast<ushort4*>(dst) = make_ushort4(ov[0], ov[1], ov[2], ov[3]);
  }
}

// Sequential core: 16 blocks, 1024 threads = 16 waves, 4 waves/SIMD.
// Per wave 2 mtiles, BOTH register-resident (64 regs) -> no LDS weight reads;
// LDS holds only h (16 KB). 4 waves/SIMD doubles the latency-hiding contexts
// (the one lever with measured wins: R11 +29%, R14 +4%). Wave kt-start
// staggered by (wv&3)*4 so SIMD-sharing waves touch different h regions.
#define KT_BODY2(KT) { \
      bf16x8 hb = __builtin_bit_cast(bf16x8, \
          *reinterpret_cast<const uint4*>(&h_lds[bcol * 512 + (((KT) * 32 + krow * 8) ^ sw)])); \
      acc[0] = __builtin_amdgcn_mfma_f32_16x16x32_bf16(wreg[0][(KT)], hb, acc[0], 0, 0, 0); \
      acc[1] = __builtin_amdgcn_mfma_f32_16x16x32_bf16(wreg[1][(KT)], hb, acc[1], 0, 0, 0); \
    }

__global__ __launch_bounds__(1024, 4)
void rnn_seq16(unsigned char* __restrict__ ws)
{
  __shared__ alignas(16) us h_lds[16 * 512];     // 16 KB, [b][h] swizzled

  const int tid  = threadIdx.x;
  const int wv   = tid >> 6;                     // 0..15
  const int lane = tid & 63;
  const int bcol = lane & 15;
  const int krow = lane >> 4;
  const int g    = blockIdx.x;                   // 0..15
  const int sw   = (bcol & 7) << 3;
  const uint4* wp4 = reinterpret_cast<const uint4*>(ws);
  us* pre = (us*)(ws + BPRE_OFF);                // pre[t] consumed -> hidden[t] written

  for (int i = tid; i < 16 * 512; i += 1024) h_lds[i] = 0;

  // register-resident weights: mtiles 2wv, 2wv+1 (64 regs)
  bf16x8 wreg[2][16];
#pragma unroll
  for (int j = 0; j < 2; ++j)
#pragma unroll
    for (int kt = 0; kt < 16; ++kt)
      wreg[j][kt] = __builtin_bit_cast(bf16x8, wp4[((2 * wv + j) * 16 + kt) * 64 + lane]);

  int h0[2];
#pragma unroll
  for (int j = 0; j < 2; ++j) h0[j] = (2 * wv + j) * 16 + krow * 4;

  __syncthreads();

  // per-thread coalesced I/O base (fragment-linear): 16 B per thread per t
  const size_t tstride = (size_t)16 * 1024 * 8;           // shorts per t
  us* pio = pre + ((size_t)g * 1024 + tid) * 8;

  uint4 pA = *reinterpret_cast<const uint4*>(pio);        // pre[t] (8 shorts)
  uint4 hs = make_uint4(0, 0, 0, 0);                      // h[t-1] (8 bf16)

#pragma unroll 1
  for (int t = 0; t < TT; ++t) {
    // store h[t-1] (regs) -> hidden[t-1]; drains at the barrier, far away
    if (t > 0)
      *reinterpret_cast<uint4*>(pio + (size_t)(t - 1) * tstride) = hs;
    // prefetch pre[t+1]
    uint4 pB = make_uint4(0, 0, 0, 0);
    if (t + 1 < TT)
      pB = *reinterpret_cast<const uint4*>(pio + (size_t)(t + 1) * tstride);

    // P1: recurrent GEMM h[t-1] @ Wrec^T (2 reg-resident mtiles),
    // wave-staggered kt start: offset (wv&3)*4
    f32x4 acc[2];
    acc[0] = f32x4{0.f, 0.f, 0.f, 0.f};
    acc[1] = f32x4{0.f, 0.f, 0.f, 0.f};
    switch (wv & 3) {
      case 0:
#pragma unroll
        for (int i = 0; i < 16; ++i) KT_BODY2(i)
        break;
      case 1:
#pragma unroll
        for (int i = 0; i < 16; ++i) KT_BODY2((i + 4) & 15)
        break;
      case 2:
#pragma unroll
        for (int i = 0; i < 16; ++i) KT_BODY2((i + 8) & 15)
        break;
      default:
#pragma unroll
        for (int i = 0; i < 16; ++i) KT_BODY2((i + 12) & 15)
        break;
    }

    // P2a: state update fully in registers (pa = pre[t], hs = h[t-1])
    {
      const us* pa = reinterpret_cast<const us*>(&pA);
      us* hh = reinterpret_cast<us*>(&hs);
#pragma unroll
      for (int j = 0; j < 2; ++j)
#pragma unroll
        for (int r = 0; r < 4; ++r) {
          int s = j * 4 + r;
          float v = acc[j][r] + bf2f(pa[s]);
          v = fmaxf(v, 0.f);
          hh[s] = f2bf(0.2f * v + 0.8f * bf2f(hh[s]));
        }
    }
    __syncthreads();   // all P1 reads of h[t-1] done
    // P2b: write h[t] B-layout into LDS
    {
      const us* hh = reinterpret_cast<const us*>(&hs);
#pragma unroll
      for (int j = 0; j < 2; ++j) {
        *reinterpret_cast<ushort4*>(&h_lds[bcol * 512 + (h0[j] ^ sw)]) =
            make_ushort4(hh[j * 4], hh[j * 4 + 1], hh[j * 4 + 2], hh[j * 4 + 3]);
      }
    }
    pA = pB;
    __syncthreads();   // h[t] visible for next step
  }

  // final hidden store
  *reinterpret_cast<uint4*>(pio + (size_t)(TT - 1) * tstride) = hs;
}

// Deferred output GEMM: out[t,b,o] = hidden[t,b,:] @ Wout^T + Wout_b
// (hidden is fragment-linear for the 1024-thread producer; decode on staging)
__global__ __launch_bounds__(256)
void out_gemm(const us* __restrict__ hid, const us* __restrict__ wp,
              const float* __restrict__ Wout_b, float* __restrict__ out)
{
  __shared__ alignas(16) us t_lds[16 * 512];
  const int tid = threadIdx.x;
  const int wv = tid >> 6, lane = tid & 63;
  const int bcol = lane & 15, krow = lane >> 4;
  const int tg = blockIdx.x;                  // t*16 + g
  const int t = tg >> 4, g = tg & 15;
  const int sw = (bcol & 7) << 3;
  const uint4* wp4 = reinterpret_cast<const uint4*>(wp);

#pragma unroll
  for (int q = 0; q < 4; ++q) {
    int cc = tid + q * 256;                   // ctid 0..1023
    uint4 v = *reinterpret_cast<const uint4*>(hid + (size_t)tg * 8192 + (size_t)cc * 8);
    us vs[8];
    *reinterpret_cast<uint4*>(&vs[0]) = v;
    int b = cc & 15, kr = (cc >> 4) & 3, mt2 = cc >> 6;
    int swb = (b & 7) << 3;
#pragma unroll
    for (int half = 0; half < 2; ++half) {
      int m = mt2 * 2 + half;
      int h = m * 16 + kr * 4;
      *reinterpret_cast<ushort4*>(&t_lds[b * 512 + (h ^ swb)]) =
          make_ushort4(vs[half * 4], vs[half * 4 + 1], vs[half * 4 + 2], vs[half * 4 + 3]);
    }
  }
  __syncthreads();
  if (wv < 3) {
    f32x4 po = {0.f, 0.f, 0.f, 0.f};
#pragma unroll
    for (int kt = 0; kt < 16; ++kt) {
      bf16x8 hb = __builtin_bit_cast(bf16x8,
          *reinterpret_cast<const uint4*>(&t_lds[bcol * 512 + ((kt * 32 + krow * 8) ^ sw)]));
      bf16x8 ao = __builtin_bit_cast(bf16x8, wp4[(FRAG_OUT_OFF + wv * 16 + kt) * 64 + lane]);
      po = __builtin_amdgcn_mfma_f32_16x16x32_bf16(ao, hb, po, 0, 0, 0);
    }
#pragma unroll
    for (int r = 0; r < 4; ++r) {
      int o = wv * 16 + krow * 4 + r;
      if (o < NOUT)
        out[((size_t)t * BB + g * 16 + bcol) * NOUT + o] = po[r] + Wout_b[o];
    }
  }
}

// ====================== FALLBACK (R7, verbatim) ===========================
__global__ __launch_bounds__(512, 2)
void rnn_fused(const float* __restrict__ x, const float* __restrict__ noise,
               const float* __restrict__ Ws_b, const float* __restrict__ Wrec_b,
               const float* __restrict__ Wout_b, unsigned char* __restrict__ ws,
               float* __restrict__ out)
{
  __shared__ alignas(16) us h_lds[16 * HALF];
  __shared__ alignas(16) us x_lds[2][16 * 128];
  __shared__ alignas(16) us win_lds[64 * 512];
  __shared__ alignas(16) us wout_lds[24 * 512];

  const int tid  = threadIdx.x;
  const int wv   = tid >> 6;
  const int lane = tid & 63;
  const int bcol = lane & 15;
  const int krow = lane >> 4;
  const int bid  = blockIdx.x;
  const int g    = bid & 15;
  const int hf   = bid >> 4;
  const int gb   = g * 16;
  const int hbase = hf * HALF;
  const int sw   = (bcol & 7) << 3;
  const bool outduty = (hf == 0);

  const uint4* wp4 = reinterpret_cast<const uint4*>(ws);
  u64* prec_own = (u64*)(ws + PREC_OFF + (size_t)bid * PREC_STRIDE);
  const u64* prec_par = (const u64*)(ws + PREC_OFF + (size_t)(bid ^ 16) * PREC_STRIDE);
  u64* pout_buf = (u64*)(ws + POUT_OFF + (size_t)g * POUT_STRIDE);

  for (int i = tid; i < 16 * HALF; i += 512) h_lds[i] = 0;
  {
    us* xz = &x_lds[0][0];
    for (int i = tid; i < 2 * 16 * 128; i += 512) xz[i] = 0;
  }
  for (int c = tid; c < 64 * 64; c += 512) {
    int fl = c >> 6, l = c & 63;
    uint4 w = wp4[(FRAG_IN_OFF + hf * 64 + fl) * 64 + l];
    *reinterpret_cast<uint4*>(&win_lds[fl * 512 + l * 8]) = w;
  }
  for (int c = tid; c < 24 * 64; c += 512) {
    int fl = c >> 6, l = c & 63;
    int mt_o = fl >> 3, kto = fl & 7;
    uint4 w = wp4[(FRAG_OUT_OFF + mt_o * 16 + hf * 8 + kto) * 64 + l];
    *reinterpret_cast<uint4*>(&wout_lds[fl * 512 + l * 8]) = w;
  }

  bf16x8 wreg_own[2][8], wreg_par[2][8];
#pragma unroll
  for (int j = 0; j < 2; ++j)
#pragma unroll
    for (int kt = 0; kt < 8; ++kt) {
      wreg_own[j][kt] = __builtin_bit_cast(bf16x8,
          wp4[((hf * 16 + 2 * wv + j) * 16 + (hf * 8 + kt)) * 64 + lane]);
      wreg_par[j][kt] = __builtin_bit_cast(bf16x8,
          wp4[(((1 - hf) * 16 + 2 * wv + j) * 16 + (hf * 8 + kt)) * 64 + lane]);
    }

  float bias_reg[2][4];
#pragma unroll
  for (int j = 0; j < 2; ++j)
#pragma unroll
    for (int r = 0; r < 4; ++r) {
      int h = hbase + (2 * wv + j) * 16 + krow * 4 + r;
      bias_reg[j][r] = Ws_b[h] + Wrec_b[h];
    }
  float woutb[4];
#pragma unroll
  for (int r = 0; r < 4; ++r) {
    int o = wv * 16 + krow * 4 + r;
    woutb[r] = (outduty && wv < 3 && o < NOUT) ? Wout_b[o] : 0.f;
  }

  const int rbase = bcol * 256 + 2 * wv * 16 + krow * 4;
  const int ri = rbase >> 1;
  const int oi = (bcol * 48 + wv * 16 + krow * 4) >> 1;

  float hreg[2][4] = {};
  f32x4 nrA[2], nrB[2];
  f32x4 po_hold = {0.f, 0.f, 0.f, 0.f};

  __syncthreads();

  if (tid < 420) {
    f32x4 xv = reinterpret_cast<const f32x4*>(x + (size_t)gb * DD)[tid];
#pragma unroll
    for (int j = 0; j < 4; ++j) {
      int e = tid * 4 + j;
      int b = e / DD, k = e - b * DD;
      x_lds[0][b * 128 + (k ^ ((b & 7) << 3))] = f2bf(xv[j]);
    }
  }
  {
    const float* nb = noise + ((size_t)gb + bcol) * HH + hbase + krow * 4;
#pragma unroll
    for (int j = 0; j < 2; ++j)
      nrA[j] = *reinterpret_cast<const f32x4*>(nb + (2 * wv + j) * 16);
  }
  __syncthreads();

#pragma unroll 1
  for (int t = 0; t < TT; ++t) {
    const int cur = t & 1;
    const unsigned tag = (unsigned)t;
    u64* prec_slot = prec_own + (size_t)(t & 1) * 2048;
    const u64* precp_slot = prec_par + (size_t)(t & 1) * 2048;
    f32x4 xs = {0.f, 0.f, 0.f, 0.f};
    if (t + 1 < TT) {
      if (tid < 420)
        xs = reinterpret_cast<const f32x4*>(x + ((size_t)(t + 1) * BB + gb) * DD)[tid];
      const float* nb = noise + (((size_t)(t + 1)) * BB + gb + bcol) * HH + hbase + krow * 4;
#pragma unroll
      for (int j = 0; j < 2; ++j)
        nrB[j] = *reinterpret_cast<const f32x4*>(nb + (2 * wv + j) * 16);
    }

    if (t > 0) {
      f32x4 pc0 = {0.f,0.f,0.f,0.f}, pc1 = {0.f,0.f,0.f,0.f};
#pragma unroll
      for (int kto = 0; kto < 8; ++kto) {
        int k0 = kto * 32 + krow * 8;
        bf16x8 hb = __builtin_bit_cast(bf16x8,
            *reinterpret_cast<const uint4*>(&h_lds[bcol * HALF + (k0 ^ sw)]));
        pc0 = __builtin_amdgcn_mfma_f32_16x16x32_bf16(wreg_par[0][kto], hb, pc0, 0, 0, 0);
        pc1 = __builtin_amdgcn_mfma_f32_16x16x32_bf16(wreg_par[1][kto], hb, pc1, 0, 0, 0);
      }
      st_agent(prec_slot + ri,     (u64)pkv(pc0[0], tag) | ((u64)pkv(pc0[1], tag) << 32));
      st_agent(prec_slot + ri + 1, (u64)pkv(pc0[2], tag) | ((u64)pkv(pc0[3], tag) << 32));
      st_agent(prec_slot + ri + 8, (u64)pkv(pc1[0], tag) | ((u64)pkv(pc1[1], tag) << 32));
      st_agent(prec_slot + ri + 9, (u64)pkv(pc1[2], tag) | ((u64)pkv(pc1[3], tag) << 32));
    }

    f32x4 acc[2];
    acc[0] = f32x4{0.f,0.f,0.f,0.f};
    acc[1] = f32x4{0.f,0.f,0.f,0.f};
#pragma unroll
    for (int kto = 0; kto < 8; ++kto) {
      int k0 = kto * 32 + krow * 8;
      bf16x8 hb = __builtin_bit_cast(bf16x8,
          *reinterpret_cast<const uint4*>(&h_lds[bcol * HALF + (k0 ^ sw)]));
      acc[0] = __builtin_amdgcn_mfma_f32_16x16x32_bf16(wreg_own[0][kto], hb, acc[0], 0, 0, 0);
      acc[1] = __builtin_amdgcn_mfma_f32_16x16x32_bf16(wreg_own[1][kto], hb, acc[1], 0, 0, 0);
    }
#pragma unroll
    for (int kx = 0; kx < 4; ++kx) {
      int k0 = kx * 32 + krow * 8;
      bf16x8 xb = __builtin_bit_cast(bf16x8,
          *reinterpret_cast<const uint4*>(&x_lds[cur][bcol * 128 + (k0 ^ sw)]));
#pragma unroll
      for (int j = 0; j < 2; ++j) {
        bf16x8 aw = __builtin_bit_cast(bf16x8,
            *reinterpret_cast<const uint4*>(&win_lds[((2 * wv + j) * 4 + kx) * 512 + lane * 8]));
        acc[j] = __builtin_amdgcn_mfma_f32_16x16x32_bf16(aw, xb, acc[j], 0, 0, 0);
      }
    }

    f32x4 po = {0.f, 0.f, 0.f, 0.f};
    if (t > 0 && wv < 3) {
#pragma unroll
      for (int kto = 0; kto < 8; ++kto) {
        int k0 = kto * 32 + krow * 8;
        bf16x8 hb = __builtin_bit_cast(bf16x8,
            *reinterpret_cast<const uint4*>(&h_lds[bcol * HALF + (k0 ^ sw)]));
        bf16x8 ao = __builtin_bit_cast(bf16x8,
            *reinterpret_cast<const uint4*>(&wout_lds[(wv * 8 + kto) * 512 + lane * 8]));
        po = __builtin_amdgcn_mfma_f32_16x16x32_bf16(ao, hb, po, 0, 0, 0);
      }
    }

    f32x4 pa0 = {0.f,0.f,0.f,0.f}, pa1 = {0.f,0.f,0.f,0.f};
    if (t > 0) {
      u64 v0, v1, v2, v3;
      int guard = RETRY_GUARD;
      for (;;) {
        v0 = ld_agent(precp_slot + ri);
        v1 = ld_agent(precp_slot + ri + 1);
        v2 = ld_agent(precp_slot + ri + 8);
        v3 = ld_agent(precp_slot + ri + 9);
        if (__all(tags4_ok(v0, v1, v2, v3, tag)) || --guard == 0) break;
        __builtin_amdgcn_s_sleep(1);
      }
      pa0[0] = bfhi((unsigned)v0); pa0[1] = bfhi((unsigned)(v0 >> 32));
      pa0[2] = bfhi((unsigned)v1); pa0[3] = bfhi((unsigned)(v1 >> 32));
      pa1[0] = bfhi((unsigned)v2); pa1[1] = bfhi((unsigned)(v2 >> 32));
      pa1[2] = bfhi((unsigned)v3); pa1[3] = bfhi((unsigned)(v3 >> 32));
      if (!outduty && wv < 3) {
        u64* ps = pout_buf + (size_t)(t & 1) * 384;
        st_agent(ps + oi,     (u64)pkv(po[0], tag) | ((u64)pkv(po[1], tag) << 32));
        st_agent(ps + oi + 1, (u64)pkv(po[2], tag) | ((u64)pkv(po[3], tag) << 32));
      }
    }

    __syncthreads();

#pragma unroll
    for (int j = 0; j < 2; ++j) {
      us hsv[4];
      f32x4 pa = j ? pa1 : pa0;
#pragma unroll
      for (int r = 0; r < 4; ++r) {
        float v = acc[j][r] + pa[r] + bias_reg[j][r] + 0.05f * nrA[j][r];
        v = fmaxf(v, 0.f);
        float hn = 0.2f * v + 0.8f * hreg[j][r];
        hreg[j][r] = hn;
        hsv[r] = f2bf(hn);
      }
      int hloc = (2 * wv + j) * 16 + krow * 4;
      *reinterpret_cast<ushort4*>(&h_lds[bcol * HALF + (hloc ^ sw)]) =
          make_ushort4(hsv[0], hsv[1], hsv[2], hsv[3]);
    }
    if (t + 1 < TT && tid < 420) {
#pragma unroll
      for (int j = 0; j < 4; ++j) {
        int e = tid * 4 + j;
        int b = e / DD, k = e - b * DD;
        x_lds[cur ^ 1][b * 128 + (k ^ ((b & 7) << 3))] = f2bf(xs[j]);
      }
    }
#pragma unroll
    for (int j = 0; j < 2; ++j) nrA[j] = nrB[j];

    if (outduty && wv < 3 && t >= 2) {
      const unsigned otag = (unsigned)(t - 1);
      const u64* ps = pout_buf + (size_t)((t - 1) & 1) * 384;
      u64 w0, w1;
      int guard = RETRY_GUARD;
      for (;;) {
        w0 = ld_agent(ps + oi);
        w1 = ld_agent(ps + oi + 1);
        if (__all(tags2_ok(w0, w1, otag)) || --guard == 0) break;
        __builtin_amdgcn_s_sleep(1);
      }
      float pr[4] = { bfhi((unsigned)w0), bfhi((unsigned)(w0 >> 32)),
                      bfhi((unsigned)w1), bfhi((unsigned)(w1 >> 32)) };
#pragma unroll
      for (int r = 0; r < 4; ++r) {
        int o = wv * 16 + krow * 4 + r;
        if (o < NOUT)
          out[((size_t)(t - 2) * BB + gb + bcol) * NOUT + o] = po_hold[r] + pr[r] + woutb[r];
      }
    }
    if (outduty && wv < 3 && t > 0) po_hold = po;

    __syncthreads();
  }

  if (!outduty && wv < 3) {
    f32x4 po = {0.f, 0.f, 0.f, 0.f};
#pragma unroll
    for (int kto = 0; kto < 8; ++kto) {
      int k0 = kto * 32 + krow * 8;
      bf16x8 hb = __builtin_bit_cast(bf16x8,
          *reinterpret_cast<const uint4*>(&h_lds[bcol * HALF + (k0 ^ sw)]));
      bf16x8 ao = __builtin_bit_cast(bf16x8,
          *reinterpret_cast<const uint4*>(&wout_lds[(wv * 8 + kto) * 512 + lane * 8]));
      po = __builtin_amdgcn_mfma_f32_16x16x32_bf16(ao, hb, po, 0, 0, 0);
    }
    const unsigned tagT = (unsigned)TT;
    u64* ps = pout_buf + (size_t)2 * 384;
    st_agent(ps + oi,     (u64)pkv(po[0], tagT) | ((u64)pkv(po[1], tagT) << 32));
    st_agent(ps + oi + 1, (u64)pkv(po[2], tagT) | ((u64)pkv(po[3], tagT) << 32));
  }
  if (outduty && wv < 3) {
    {
      const unsigned otag = (unsigned)(TT - 1);
      const u64* ps = pout_buf + (size_t)((TT - 1) & 1) * 384;
      u64 w0, w1;
      int guard = RETRY_GUARD;
      for (;;) {
        w0 = ld_agent(ps + oi);
        w1 = ld_agent(ps + oi + 1);
        if (__all(tags2_ok(w0, w1, otag)) || --guard == 0) break;
        __builtin_amdgcn_s_sleep(1);
      }
      float pr[4] = { bfhi((unsigned)w0), bfhi((unsigned)(w0 >> 32)),
                      bfhi((unsigned)w1), bfhi((unsigned)(w1 >> 32)) };
#pragma unroll
      for (int r = 0; r < 4; ++r) {
        int o = wv * 16 + krow * 4 + r;
        if (o < NOUT)
          out[((size_t)(TT - 2) * BB + gb + bcol) * NOUT + o] = po_hold[r] + pr[r] + woutb[r];
      }
    }
    {
      f32x4 po = {0.f, 0.f, 0.f, 0.f};
#pragma unroll
      for (int kto = 0; kto < 8; ++kto) {
        int k0 = kto * 32 + krow * 8;
        bf16x8 hb = __builtin_bit_cast(bf16x8,
            *reinterpret_cast<const uint4*>(&h_lds[bcol * HALF + (k0 ^ sw)]));
        bf16x8 ao = __builtin_bit_cast(bf16x8,
            *reinterpret_cast<const uint4*>(&wout_lds[(wv * 8 + kto) * 512 + lane * 8]));
        po = __builtin_amdgcn_mfma_f32_16x16x32_bf16(ao, hb, po, 0, 0, 0);
      }
      const unsigned tagT = (unsigned)TT;
      const u64* ps = pout_buf + (size_t)2 * 384;
      u64 w0, w1;
      int guard = RETRY_GUARD;
      for (;;) {
        w0 = ld_agent(ps + oi);
        w1 = ld_agent(ps + oi + 1);
        if (__all(tags2_ok(w0, w1, tagT)) || --guard == 0) break;
        __builtin_amdgcn_s_sleep(1);
      }
      float pr[4] = { bfhi((unsigned)w0), bfhi((unsigned)(w0 >> 32)),
                      bfhi((unsigned)w1), bfhi((unsigned)(w1 >> 32)) };
#pragma unroll
      for (int r = 0; r < 4; ++r) {
        int o = wv * 16 + krow * 4 + r;
        if (o < NOUT)
          out[((size_t)(TT - 1) * BB + gb + bcol) * NOUT + o] = po[r] + pr[r] + woutb[r];
      }
    }
  }
}

extern "C" void kernel_launch(void* const* d_in, const int* in_sizes, int n_in,
                              void* d_out, int out_size, void* d_ws, size_t ws_size,
                              hipStream_t stream) {
  (void)in_sizes; (void)n_in; (void)out_size;
  const float* x      = (const float*)d_in[0];
  const float* noise  = (const float*)d_in[1];
  const float* Ws_w   = (const float*)d_in[2];
  const float* Ws_b   = (const float*)d_in[3];
  const float* Wr_w   = (const float*)d_in[4];
  const float* Wrec_w = (const float*)d_in[5];
  const float* Wrec_b = (const float*)d_in[6];
  const float* mask   = (const float*)d_in[7];
  const float* Wout_w = (const float*)d_in[8];
  const float* Wout_b = (const float*)d_in[9];
  unsigned char* ws   = (unsigned char*)d_ws;
  float* out          = (float*)d_out;

  pack_weights<<<(NFRAG_TOT * 64 + 255) / 256, 256, 0, stream>>>(
      Ws_w, Wr_w, Wrec_w, mask, Wout_w, (us*)ws);

  if (ws_size >= (size_t)SNEED) {
    us* pre = (us*)(ws + BPRE_OFF);
    precompute_pre<<<TT * 16, 512, 0, stream>>>(x, noise, Ws_b, Wrec_b, (us*)ws, pre);
    rnn_seq16<<<16, 1024, 0, stream>>>(ws);
    out_gemm<<<TT * 16, 256, 0, stream>>>(pre, (us*)ws, Wout_b, out);
  } else {
    hipMemsetAsync(ws + PREC_OFF, 0, EXCH_BYTES, stream);
    rnn_fused<<<32, 512, 0, stream>>>(x, noise, Ws_b, Wrec_b, Wout_b, ws, out);
  }
}

// Round 16
// 1649.235 us; speedup vs baseline: 2.4368x; 2.4368x over previous
//
#include <hip/hip_runtime.h>

#define TT 512
#define BB 256
#define HH 512
#define DD 105
#define RS 85
#define NRULE 20
#define NOUT 33
#define HALF 256

#define NFRAG_REC 512              // 32 mtiles x 16 ktiles
#define NFRAG_IN  128              // 32 mtiles x 4 ktiles (k padded 105->128)
#define NFRAG_OUT 48               // 3 mtiles (o padded 33->48) x 16 ktiles
#define FRAG_IN_OFF  (NFRAG_REC)
#define FRAG_OUT_OFF (NFRAG_REC + NFRAG_IN)
#define NFRAG_TOT (NFRAG_REC + NFRAG_IN + NFRAG_OUT)

#define WP_BYTES    ((size_t)NFRAG_TOT * 1024)         // 704512

// ---- fallback (R7) layout ----
#define PREC_OFF    WP_BYTES
#define PREC_STRIDE ((size_t)32768)
#define POUT_OFF    (PREC_OFF + 32 * PREC_STRIDE)
#define POUT_STRIDE ((size_t)9216)
#define EXCH_BYTES  (32 * PREC_STRIDE + 16 * POUT_STRIDE)

// ---- big-path layout: wp | pre/hidden (aliased, fragment-linear) ----
// pre element (t, g, src_tid in [0,512), slot s=j*4+r) at short offset
//   ((t*16+g)*512 + src_tid)*16 + s
// holds value for b = src_tid&15,
//   h = ((src_tid>>6)*4 + (s>>2))*16 + ((src_tid>>4)&3)*4 + (s&3)
#define BPRE_OFF    WP_BYTES
#define BPRE_BYTES  ((size_t)TT * 16 * 16 * 512 * 2)   // 134217728
#define SNEED       (BPRE_OFF + BPRE_BYTES)            // 134922240

#define RETRY_GUARD 100000

typedef __bf16 bf16x8 __attribute__((ext_vector_type(8)));
typedef float  f32x4  __attribute__((ext_vector_type(4)));
typedef unsigned long long u64;
typedef unsigned short us;

__device__ __forceinline__ us f2bf(float f) {
  unsigned u = __builtin_bit_cast(unsigned, f);
  u += 0x7FFFu + ((u >> 16) & 1u);            // RNE
  return (us)(u >> 16);
}
__device__ __forceinline__ float bf2f(us v) {
  return __builtin_bit_cast(float, (unsigned)v << 16);
}
__device__ __forceinline__ u64 ld_agent(const u64* p) {
  return __hip_atomic_load(p, __ATOMIC_RELAXED, __HIP_MEMORY_SCOPE_AGENT);
}
__device__ __forceinline__ void st_agent(u64* p, u64 v) {
  __hip_atomic_store(p, v, __ATOMIC_RELAXED, __HIP_MEMORY_SCOPE_AGENT);
}
__device__ __forceinline__ float bfhi(unsigned w) {
  return __builtin_bit_cast(float, w & 0xffff0000u);
}
__device__ __forceinline__ unsigned pkv(float v, unsigned tag) {
  return ((unsigned)f2bf(v) << 16) | tag;
}
__device__ __forceinline__ int tags4_ok(u64 v0, u64 v1, u64 v2, u64 v3, unsigned tag) {
  return (((unsigned)v0 & 0xffffu) == tag) & (((unsigned)(v0 >> 32) & 0xffffu) == tag)
       & (((unsigned)v1 & 0xffffu) == tag) & (((unsigned)(v1 >> 32) & 0xffffu) == tag)
       & (((unsigned)v2 & 0xffffu) == tag) & (((unsigned)(v2 >> 32) & 0xffffu) == tag)
       & (((unsigned)v3 & 0xffffu) == tag) & (((unsigned)(v3 >> 32) & 0xffffu) == tag);
}
__device__ __forceinline__ int tags2_ok(u64 v0, u64 v1, unsigned tag) {
  return (((unsigned)v0 & 0xffffu) == tag) & (((unsigned)(v0 >> 32) & 0xffffu) == tag)
       & (((unsigned)v1 & 0xffffu) == tag) & (((unsigned)(v1 >> 32) & 0xffffu) == tag);
}

// Pack Wrec*mask, [Ws|Wr] (k padded to 128), Wout (m padded to 48) into MFMA
// 16x16x32 A-frag layout: frag f, lane l holds M[mt*16+(l&15)][kt*32+(l>>4)*8+j]
__global__ void pack_weights(const float* __restrict__ Ws_w, const float* __restrict__ Wr_w,
                             const float* __restrict__ Wrec_w, const float* __restrict__ mask,
                             const float* __restrict__ Wout_w, us* __restrict__ wp)
{
  int gid = blockIdx.x * blockDim.x + threadIdx.x;
  if (gid >= NFRAG_TOT * 64) return;
  int f = gid >> 6, lane = gid & 63;
  int m16 = lane & 15, kg = lane >> 4;
  float v[8];
  if (f < NFRAG_REC) {
    int mt = f >> 4, kt = f & 15;
    int m = mt * 16 + m16, k0 = kt * 32 + kg * 8;
#pragma unroll
    for (int j = 0; j < 8; ++j) {
      int k = k0 + j;
      v[j] = Wrec_w[m * HH + k] * mask[m * HH + k];
    }
  } else if (f < FRAG_OUT_OFF) {
    int ff = f - FRAG_IN_OFF;
    int mt = ff >> 2, kt = ff & 3;
    int m = mt * 16 + m16, k0 = kt * 32 + kg * 8;
#pragma unroll
    for (int j = 0; j < 8; ++j) {
      int k = k0 + j;
      float val = 0.f;
      if (k < RS) val = Ws_w[m * RS + k];
      else if (k < DD) val = Wr_w[m * NRULE + (k - RS)];
      v[j] = val;
    }
  } else {
    int ff = f - FRAG_OUT_OFF;
    int mt = ff >> 4, kt = ff & 15;
    int m = mt * 16 + m16, k0 = kt * 32 + kg * 8;
#pragma unroll
    for (int j = 0; j < 8; ++j) {
      int k = k0 + j;
      v[j] = (m < NOUT) ? Wout_w[m * HH + k] : 0.f;
    }
  }
  unsigned o[4];
#pragma unroll
  for (int j = 0; j < 4; ++j)
    o[j] = (unsigned)f2bf(v[2 * j]) | ((unsigned)f2bf(v[2 * j + 1]) << 16);
  uint4 st = make_uint4(o[0], o[1], o[2], o[3]);
  *reinterpret_cast<uint4*>(wp + (size_t)f * 512 + lane * 8) = st;
}

// ============================ BIG PATH ====================================
// pre (fragment-linear) = x@Win^T + biases + sigma*noise
__global__ __launch_bounds__(512)
void precompute_pre(const float* __restrict__ x, const float* __restrict__ noise,
                    const float* __restrict__ Ws_b, const float* __restrict__ Wrec_b,
                    const us* __restrict__ wp, us* __restrict__ pre)
{
  __shared__ alignas(16) us x_lds[16 * 128];
  const int t  = blockIdx.x >> 4;
  const int gg = blockIdx.x & 15;
  const int gb = gg * 16;
  const int tid = threadIdx.x;
  const int wv = tid >> 6, lane = tid & 63;
  const int bcol = lane & 15, krow = lane >> 4;
  const int sw = (bcol & 7) << 3;
  const uint4* wp4 = reinterpret_cast<const uint4*>(wp);

  for (int i = tid; i < 16 * 128; i += 512) x_lds[i] = 0;
  __syncthreads();
  if (tid < 420) {
    f32x4 xv = reinterpret_cast<const f32x4*>(x + ((size_t)t * BB + gb) * DD)[tid];
#pragma unroll
    for (int j = 0; j < 4; ++j) {
      int e = tid * 4 + j;
      int b = e / DD, k = e - b * DD;
      x_lds[b * 128 + (k ^ ((b & 7) << 3))] = f2bf(xv[j]);
    }
  }
  __syncthreads();

  us ov[16];
#pragma unroll
  for (int jj = 0; jj < 4; ++jj) {
    int m = wv * 4 + jj;                         // 0..31
    f32x4 acc = {0.f, 0.f, 0.f, 0.f};
#pragma unroll
    for (int kx = 0; kx < 4; ++kx) {
      int k0 = kx * 32 + krow * 8;
      bf16x8 xb = __builtin_bit_cast(bf16x8,
          *reinterpret_cast<const uint4*>(&x_lds[bcol * 128 + (k0 ^ sw)]));
      bf16x8 aw = __builtin_bit_cast(bf16x8, wp4[(FRAG_IN_OFF + m * 4 + kx) * 64 + lane]);
      acc = __builtin_amdgcn_mfma_f32_16x16x32_bf16(aw, xb, acc, 0, 0, 0);
    }
    int h0 = m * 16 + krow * 4;
    f32x4 b1 = *reinterpret_cast<const f32x4*>(Ws_b + h0);
    f32x4 b2 = *reinterpret_cast<const f32x4*>(Wrec_b + h0);
    f32x4 nz = *reinterpret_cast<const f32x4*>(noise + ((size_t)t * BB + gb + bcol) * HH + h0);
#pragma unroll
    for (int r = 0; r < 4; ++r)
      ov[jj * 4 + r] = f2bf(acc[r] + b1[r] + b2[r] + 0.05f * nz[r]);
  }
  // thread's 16 values -> one contiguous 32 B chunk (matches seq thread tid)
  us* dst = pre + (((size_t)t * 16 + gg) * 512 + tid) * 16;
  *reinterpret_cast<uint4*>(dst)     = *reinterpret_cast<uint4*>(&ov[0]);
  *reinterpret_cast<uint4*>(dst + 8) = *reinterpret_cast<uint4*>(&ov[8]);
}

// Sequential core (R11 structure + SIMD-pair phase stagger) — best measured:
// 16 blocks, 512 threads = 8 waves, 2 waves/SIMD. Per wave 4 mtiles:
// 3 register-resident (192 regs) + 1 in LDS. Waves 0-3 iterate kt=0..15,
// waves 4-7 iterate kt=8..15,0..7 so SIMD-sharing waves touch different
// LDS regions at any moment.
#define KT_BODY(KT) { \
      bf16x8 hb = __builtin_bit_cast(bf16x8, \
          *reinterpret_cast<const uint4*>(&h_lds[bcol * 512 + (((KT) * 32 + krow * 8) ^ sw)])); \
      acc[0] = __builtin_amdgcn_mfma_f32_16x16x32_bf16(wreg[0][(KT)], hb, acc[0], 0, 0, 0); \
      acc[1] = __builtin_amdgcn_mfma_f32_16x16x32_bf16(wreg[1][(KT)], hb, acc[1], 0, 0, 0); \
      acc[2] = __builtin_amdgcn_mfma_f32_16x16x32_bf16(wreg[2][(KT)], hb, acc[2], 0, 0, 0); \
      bf16x8 wl = __builtin_bit_cast(bf16x8, \
          *reinterpret_cast<const uint4*>(&wlds[(wv * 16 + (KT)) * 512 + lane * 8])); \
      acc[3] = __builtin_amdgcn_mfma_f32_16x16x32_bf16(wl, hb, acc[3], 0, 0, 0); \
    }

__global__ __launch_bounds__(512, 2)
void rnn_seq16(unsigned char* __restrict__ ws)
{
  __shared__ alignas(16) us h_lds[16 * 512];     // 16 KB, [b][h] swizzled
  __shared__ alignas(16) us wlds[128 * 512];     // 128 KB: 8 waves x 16 frags

  const int tid  = threadIdx.x;
  const int wv   = tid >> 6;                     // 0..7
  const int lane = tid & 63;
  const int bcol = lane & 15;
  const int krow = lane >> 4;
  const int g    = blockIdx.x;                   // 0..15
  const int sw   = (bcol & 7) << 3;
  const uint4* wp4 = reinterpret_cast<const uint4*>(ws);
  us* pre = (us*)(ws + BPRE_OFF);                // pre[t] consumed -> hidden[t] written

  for (int i = tid; i < 16 * 512; i += 512) h_lds[i] = 0;
  // stage LDS weight frags: wave w's 4th mtile (4w+3)
  for (int c = tid; c < 128 * 64; c += 512) {
    int fl = c >> 6, l = c & 63;
    int w = fl >> 4, kt = fl & 15;
    int mt = 4 * w + 3;
    uint4 v = wp4[(mt * 16 + kt) * 64 + l];
    *reinterpret_cast<uint4*>(&wlds[fl * 512 + l * 8]) = v;
  }

  // register-resident weights: mtiles 4wv+0..2 (192 regs)
  bf16x8 wreg[3][16];
#pragma unroll
  for (int j = 0; j < 3; ++j)
#pragma unroll
    for (int kt = 0; kt < 16; ++kt)
      wreg[j][kt] = __builtin_bit_cast(bf16x8, wp4[((4 * wv + j) * 16 + kt) * 64 + lane]);

  int h0[4];
#pragma unroll
  for (int j = 0; j < 4; ++j) h0[j] = (4 * wv + j) * 16 + krow * 4;

  __syncthreads();

  // per-thread coalesced I/O base (fragment-linear): 32 B per thread per t
  const size_t tstride = (size_t)16 * 512 * 16;           // shorts per t
  us* pio = pre + ((size_t)g * 512 + tid) * 16;

  uint4 pA[2];                                   // pre[t] (16 shorts)
  pA[0] = *reinterpret_cast<const uint4*>(pio);
  pA[1] = *reinterpret_cast<const uint4*>(pio + 8);

  uint4 hs[2] = {};                              // h[t-1] C-layout (16 bf16), zero

#pragma unroll 1
  for (int t = 0; t < TT; ++t) {
    // store h[t-1] (regs) -> hidden[t-1]; drains ~2k cy later at the barrier
    if (t > 0) {
      us* hout = pio + (size_t)(t - 1) * tstride;
      *reinterpret_cast<uint4*>(hout)     = hs[0];
      *reinterpret_cast<uint4*>(hout + 8) = hs[1];
    }
    // prefetch pre[t+1]
    uint4 pB[2];
    if (t + 1 < TT) {
      const us* pn = pio + (size_t)(t + 1) * tstride;
      pB[0] = *reinterpret_cast<const uint4*>(pn);
      pB[1] = *reinterpret_cast<const uint4*>(pn + 8);
    }

    // P1: recurrent GEMM h[t-1] @ Wrec^T (4 mtiles: 3 reg + 1 LDS),
    // SIMD-pair staggered kt order.
    f32x4 acc[4];
#pragma unroll
    for (int j = 0; j < 4; ++j) acc[j] = f32x4{0.f, 0.f, 0.f, 0.f};
    if (wv < 4) {
#pragma unroll
      for (int i = 0; i < 16; ++i) KT_BODY(i)
    } else {
#pragma unroll
      for (int i = 0; i < 16; ++i) KT_BODY((i + 8) & 15)
    }

    // P2a: state update fully in registers (pa = pre[t], hs = h[t-1])
    {
      const us* pa = reinterpret_cast<const us*>(pA);
      us* hh = reinterpret_cast<us*>(hs);
#pragma unroll
      for (int j = 0; j < 4; ++j)
#pragma unroll
        for (int r = 0; r < 4; ++r) {
          int s = j * 4 + r;
          float v = acc[j][r] + bf2f(pa[s]);
          v = fmaxf(v, 0.f);
          hh[s] = f2bf(0.2f * v + 0.8f * bf2f(hh[s]));
        }
    }
    __syncthreads();   // all P1 reads of h[t-1] done
    // P2b: write h[t] B-layout into LDS
    {
      const us* hh = reinterpret_cast<const us*>(hs);
#pragma unroll
      for (int j = 0; j < 4; ++j) {
        *reinterpret_cast<ushort4*>(&h_lds[bcol * 512 + (h0[j] ^ sw)]) =
            make_ushort4(hh[j * 4], hh[j * 4 + 1], hh[j * 4 + 2], hh[j * 4 + 3]);
      }
    }
    pA[0] = pB[0];
    pA[1] = pB[1];
    __syncthreads();   // h[t] visible for next step
  }

  // final hidden store
  {
    us* hout = pio + (size_t)(TT - 1) * tstride;
    *reinterpret_cast<uint4*>(hout)     = hs[0];
    *reinterpret_cast<uint4*>(hout + 8) = hs[1];
  }
}

// Deferred output GEMM: out[t,b,o] = hidden[t,b,:] @ Wout^T + Wout_b
// (hidden is fragment-linear for 512-thread producer; decode while staging)
__global__ __launch_bounds__(256)
void out_gemm(const us* __restrict__ hid, const us* __restrict__ wp,
              const float* __restrict__ Wout_b, float* __restrict__ out)
{
  __shared__ alignas(16) us t_lds[16 * 512];
  const int tid = threadIdx.x;
  const int wv = tid >> 6, lane = tid & 63;
  const int bcol = lane & 15, krow = lane >> 4;
  const int tg = blockIdx.x;                  // t*16 + g
  const int t = tg >> 4, g = tg & 15;
  const int sw = (bcol & 7) << 3;
  const uint4* wp4 = reinterpret_cast<const uint4*>(wp);

#pragma unroll
  for (int q = 0; q < 2; ++q) {
    int cc = tid + q * 256;                   // src_tid 0..511
    const us* src = hid + (size_t)tg * 8192 + (size_t)cc * 16;
    uint4 v0 = *reinterpret_cast<const uint4*>(src);
    uint4 v1 = *reinterpret_cast<const uint4*>(src + 8);
    us vs[16];
    *reinterpret_cast<uint4*>(&vs[0]) = v0;
    *reinterpret_cast<uint4*>(&vs[8]) = v1;
    int b = cc & 15, kr = (cc >> 4) & 3;
    int swb = (b & 7) << 3;
#pragma unroll
    for (int jj = 0; jj < 4; ++jj) {
      int m = (cc >> 6) * 4 + jj;
      int h = m * 16 + kr * 4;
      *reinterpret_cast<ushort4*>(&t_lds[b * 512 + (h ^ swb)]) =
          make_ushort4(vs[jj * 4], vs[jj * 4 + 1], vs[jj * 4 + 2], vs[jj * 4 + 3]);
    }
  }
  __syncthreads();
  if (wv < 3) {
    f32x4 po = {0.f, 0.f, 0.f, 0.f};
#pragma unroll
    for (int kt = 0; kt < 16; ++kt) {
      bf16x8 hb = __builtin_bit_cast(bf16x8,
          *reinterpret_cast<const uint4*>(&t_lds[bcol * 512 + ((kt * 32 + krow * 8) ^ sw)]));
      bf16x8 ao = __builtin_bit_cast(bf16x8, wp4[(FRAG_OUT_OFF + wv * 16 + kt) * 64 + lane]);
      po = __builtin_amdgcn_mfma_f32_16x16x32_bf16(ao, hb, po, 0, 0, 0);
    }
#pragma unroll
    for (int r = 0; r < 4; ++r) {
      int o = wv * 16 + krow * 4 + r;
      if (o < NOUT)
        out[((size_t)t * BB + g * 16 + bcol) * NOUT + o] = po[r] + Wout_b[o];
    }
  }
}

// ====================== FALLBACK (R7, verbatim) ===========================
__global__ __launch_bounds__(512, 2)
void rnn_fused(const float* __restrict__ x, const float* __restrict__ noise,
               const float* __restrict__ Ws_b, const float* __restrict__ Wrec_b,
               const float* __restrict__ Wout_b, unsigned char* __restrict__ ws,
               float* __restrict__ out)
{
  __shared__ alignas(16) us h_lds[16 * HALF];
  __shared__ alignas(16) us x_lds[2][16 * 128];
  __shared__ alignas(16) us win_lds[64 * 512];
  __shared__ alignas(16) us wout_lds[24 * 512];

  const int tid  = threadIdx.x;
  const int wv   = tid >> 6;
  const int lane = tid & 63;
  const int bcol = lane & 15;
  const int krow = lane >> 4;
  const int bid  = blockIdx.x;
  const int g    = bid & 15;
  const int hf   = bid >> 4;
  const int gb   = g * 16;
  const int hbase = hf * HALF;
  const int sw   = (bcol & 7) << 3;
  const bool outduty = (hf == 0);

  const uint4* wp4 = reinterpret_cast<const uint4*>(ws);
  u64* prec_own = (u64*)(ws + PREC_OFF + (size_t)bid * PREC_STRIDE);
  const u64* prec_par = (const u64*)(ws + PREC_OFF + (size_t)(bid ^ 16) * PREC_STRIDE);
  u64* pout_buf = (u64*)(ws + POUT_OFF + (size_t)g * POUT_STRIDE);

  for (int i = tid; i < 16 * HALF; i += 512) h_lds[i] = 0;
  {
    us* xz = &x_lds[0][0];
    for (int i = tid; i < 2 * 16 * 128; i += 512) xz[i] = 0;
  }
  for (int c = tid; c < 64 * 64; c += 512) {
    int fl = c >> 6, l = c & 63;
    uint4 w = wp4[(FRAG_IN_OFF + hf * 64 + fl) * 64 + l];
    *reinterpret_cast<uint4*>(&win_lds[fl * 512 + l * 8]) = w;
  }
  for (int c = tid; c < 24 * 64; c += 512) {
    int fl = c >> 6, l = c & 63;
    int mt_o = fl >> 3, kto = fl & 7;
    uint4 w = wp4[(FRAG_OUT_OFF + mt_o * 16 + hf * 8 + kto) * 64 + l];
    *reinterpret_cast<uint4*>(&wout_lds[fl * 512 + l * 8]) = w;
  }

  bf16x8 wreg_own[2][8], wreg_par[2][8];
#pragma unroll
  for (int j = 0; j < 2; ++j)
#pragma unroll
    for (int kt = 0; kt < 8; ++kt) {
      wreg_own[j][kt] = __builtin_bit_cast(bf16x8,
          wp4[((hf * 16 + 2 * wv + j) * 16 + (hf * 8 + kt)) * 64 + lane]);
      wreg_par[j][kt] = __builtin_bit_cast(bf16x8,
          wp4[(((1 - hf) * 16 + 2 * wv + j) * 16 + (hf * 8 + kt)) * 64 + lane]);
    }

  float bias_reg[2][4];
#pragma unroll
  for (int j = 0; j < 2; ++j)
#pragma unroll
    for (int r = 0; r < 4; ++r) {
      int h = hbase + (2 * wv + j) * 16 + krow * 4 + r;
      bias_reg[j][r] = Ws_b[h] + Wrec_b[h];
    }
  float woutb[4];
#pragma unroll
  for (int r = 0; r < 4; ++r) {
    int o = wv * 16 + krow * 4 + r;
    woutb[r] = (outduty && wv < 3 && o < NOUT) ? Wout_b[o] : 0.f;
  }

  const int rbase = bcol * 256 + 2 * wv * 16 + krow * 4;
  const int ri = rbase >> 1;
  const int oi = (bcol * 48 + wv * 16 + krow * 4) >> 1;

  float hreg[2][4] = {};
  f32x4 nrA[2], nrB[2];
  f32x4 po_hold = {0.f, 0.f, 0.f, 0.f};

  __syncthreads();

  if (tid < 420) {
    f32x4 xv = reinterpret_cast<const f32x4*>(x + (size_t)gb * DD)[tid];
#pragma unroll
    for (int j = 0; j < 4; ++j) {
      int e = tid * 4 + j;
      int b = e / DD, k = e - b * DD;
      x_lds[0][b * 128 + (k ^ ((b & 7) << 3))] = f2bf(xv[j]);
    }
  }
  {
    const float* nb = noise + ((size_t)gb + bcol) * HH + hbase + krow * 4;
#pragma unroll
    for (int j = 0; j < 2; ++j)
      nrA[j] = *reinterpret_cast<const f32x4*>(nb + (2 * wv + j) * 16);
  }
  __syncthreads();

#pragma unroll 1
  for (int t = 0; t < TT; ++t) {
    const int cur = t & 1;
    const unsigned tag = (unsigned)t;
    u64* prec_slot = prec_own + (size_t)(t & 1) * 2048;
    const u64* precp_slot = prec_par + (size_t)(t & 1) * 2048;
    f32x4 xs = {0.f, 0.f, 0.f, 0.f};
    if (t + 1 < TT) {
      if (tid < 420)
        xs = reinterpret_cast<const f32x4*>(x + ((size_t)(t + 1) * BB + gb) * DD)[tid];
      const float* nb = noise + (((size_t)(t + 1)) * BB + gb + bcol) * HH + hbase + krow * 4;
#pragma unroll
      for (int j = 0; j < 2; ++j)
        nrB[j] = *reinterpret_cast<const f32x4*>(nb + (2 * wv + j) * 16);
    }

    if (t > 0) {
      f32x4 pc0 = {0.f,0.f,0.f,0.f}, pc1 = {0.f,0.f,0.f,0.f};
#pragma unroll
      for (int kto = 0; kto < 8; ++kto) {
        int k0 = kto * 32 + krow * 8;
        bf16x8 hb = __builtin_bit_cast(bf16x8,
            *reinterpret_cast<const uint4*>(&h_lds[bcol * HALF + (k0 ^ sw)]));
        pc0 = __builtin_amdgcn_mfma_f32_16x16x32_bf16(wreg_par[0][kto], hb, pc0, 0, 0, 0);
        pc1 = __builtin_amdgcn_mfma_f32_16x16x32_bf16(wreg_par[1][kto], hb, pc1, 0, 0, 0);
      }
      st_agent(prec_slot + ri,     (u64)pkv(pc0[0], tag) | ((u64)pkv(pc0[1], tag) << 32));
      st_agent(prec_slot + ri + 1, (u64)pkv(pc0[2], tag) | ((u64)pkv(pc0[3], tag) << 32));
      st_agent(prec_slot + ri + 8, (u64)pkv(pc1[0], tag) | ((u64)pkv(pc1[1], tag) << 32));
      st_agent(prec_slot + ri + 9, (u64)pkv(pc1[2], tag) | ((u64)pkv(pc1[3], tag) << 32));
    }

    f32x4 acc[2];
    acc[0] = f32x4{0.f,0.f,0.f,0.f};
    acc[1] = f32x4{0.f,0.f,0.f,0.f};
#pragma unroll
    for (int kto = 0; kto < 8; ++kto) {
      int k0 = kto * 32 + krow * 8;
      bf16x8 hb = __builtin_bit_cast(bf16x8,
          *reinterpret_cast<const uint4*>(&h_lds[bcol * HALF + (k0 ^ sw)]));
      acc[0] = __builtin_amdgcn_mfma_f32_16x16x32_bf16(wreg_own[0][kto], hb, acc[0], 0, 0, 0);
      acc[1] = __builtin_amdgcn_mfma_f32_16x16x32_bf16(wreg_own[1][kto], hb, acc[1], 0, 0, 0);
    }
#pragma unroll
    for (int kx = 0; kx < 4; ++kx) {
      int k0 = kx * 32 + krow * 8;
      bf16x8 xb = __builtin_bit_cast(bf16x8,
          *reinterpret_cast<const uint4*>(&x_lds[cur][bcol * 128 + (k0 ^ sw)]));
#pragma unroll
      for (int j = 0; j < 2; ++j) {
        bf16x8 aw = __builtin_bit_cast(bf16x8,
            *reinterpret_cast<const uint4*>(&win_lds[((2 * wv + j) * 4 + kx) * 512 + lane * 8]));
        acc[j] = __builtin_amdgcn_mfma_f32_16x16x32_bf16(aw, xb, acc[j], 0, 0, 0);
      }
    }

    f32x4 po = {0.f, 0.f, 0.f, 0.f};
    if (t > 0 && wv < 3) {
#pragma unroll
      for (int kto = 0; kto < 8; ++kto) {
        int k0 = kto * 32 + krow * 8;
        bf16x8 hb = __builtin_bit_cast(bf16x8,
            *reinterpret_cast<const uint4*>(&h_lds[bcol * HALF + (k0 ^ sw)]));
        bf16x8 ao = __builtin_bit_cast(bf16x8,
            *reinterpret_cast<const uint4*>(&wout_lds[(wv * 8 + kto) * 512 + lane * 8]));
        po = __builtin_amdgcn_mfma_f32_16x16x32_bf16(ao, hb, po, 0, 0, 0);
      }
    }

    f32x4 pa0 = {0.f,0.f,0.f,0.f}, pa1 = {0.f,0.f,0.f,0.f};
    if (t > 0) {
      u64 v0, v1, v2, v3;
      int guard = RETRY_GUARD;
      for (;;) {
        v0 = ld_agent(precp_slot + ri);
        v1 = ld_agent(precp_slot + ri + 1);
        v2 = ld_agent(precp_slot + ri + 8);
        v3 = ld_agent(precp_slot + ri + 9);
        if (__all(tags4_ok(v0, v1, v2, v3, tag)) || --guard == 0) break;
        __builtin_amdgcn_s_sleep(1);
      }
      pa0[0] = bfhi((unsigned)v0); pa0[1] = bfhi((unsigned)(v0 >> 32));
      pa0[2] = bfhi((unsigned)v1); pa0[3] = bfhi((unsigned)(v1 >> 32));
      pa1[0] = bfhi((unsigned)v2); pa1[1] = bfhi((unsigned)(v2 >> 32));
      pa1[2] = bfhi((unsigned)v3); pa1[3] = bfhi((unsigned)(v3 >> 32));
      if (!outduty && wv < 3) {
        u64* ps = pout_buf + (size_t)(t & 1) * 384;
        st_agent(ps + oi,     (u64)pkv(po[0], tag) | ((u64)pkv(po[1], tag) << 32));
        st_agent(ps + oi + 1, (u64)pkv(po[2], tag) | ((u64)pkv(po[3], tag) << 32));
      }
    }

    __syncthreads();

#pragma unroll
    for (int j = 0; j < 2; ++j) {
      us hsv[4];
      f32x4 pa = j ? pa1 : pa0;
#pragma unroll
      for (int r = 0; r < 4; ++r) {
        float v = acc[j][r] + pa[r] + bias_reg[j][r] + 0.05f * nrA[j][r];
        v = fmaxf(v, 0.f);
        float hn = 0.2f * v + 0.8f * hreg[j][r];
        hreg[j][r] = hn;
        hsv[r] = f2bf(hn);
      }
      int hloc = (2 * wv + j) * 16 + krow * 4;
      *reinterpret_cast<ushort4*>(&h_lds[bcol * HALF + (hloc ^ sw)]) =
          make_ushort4(hsv[0], hsv[1], hsv[2], hsv[3]);
    }
    if (t + 1 < TT && tid < 420) {
#pragma unroll
      for (int j = 0; j < 4; ++j) {
        int e = tid * 4 + j;
        int b = e / DD, k = e - b * DD;
        x_lds[cur ^ 1][b * 128 + (k ^ ((b & 7) << 3))] = f2bf(xs[j]);
      }
    }
#pragma unroll
    for (int j = 0; j < 2; ++j) nrA[j] = nrB[j];

    if (outduty && wv < 3 && t >= 2) {
      const unsigned otag = (unsigned)(t - 1);
      const u64* ps = pout_buf + (size_t)((t - 1) & 1) * 384;
      u64 w0, w1;
      int guard = RETRY_GUARD;
      for (;;) {
        w0 = ld_agent(ps + oi);
        w1 = ld_agent(ps + oi + 1);
        if (__all(tags2_ok(w0, w1, otag)) || --guard == 0) break;
        __builtin_amdgcn_s_sleep(1);
      }
      float pr[4] = { bfhi((unsigned)w0), bfhi((unsigned)(w0 >> 32)),
                      bfhi((unsigned)w1), bfhi((unsigned)(w1 >> 32)) };
#pragma unroll
      for (int r = 0; r < 4; ++r) {
        int o = wv * 16 + krow * 4 + r;
        if (o < NOUT)
          out[((size_t)(t - 2) * BB + gb + bcol) * NOUT + o] = po_hold[r] + pr[r] + woutb[r];
      }
    }
    if (outduty && wv < 3 && t > 0) po_hold = po;

    __syncthreads();
  }

  if (!outduty && wv < 3) {
    f32x4 po = {0.f, 0.f, 0.f, 0.f};
#pragma unroll
    for (int kto = 0; kto < 8; ++kto) {
      int k0 = kto * 32 + krow * 8;
      bf16x8 hb = __builtin_bit_cast(bf16x8,
          *reinterpret_cast<const uint4*>(&h_lds[bcol * HALF + (k0 ^ sw)]));
      bf16x8 ao = __builtin_bit_cast(bf16x8,
          *reinterpret_cast<const uint4*>(&wout_lds[(wv * 8 + kto) * 512 + lane * 8]));
      po = __builtin_amdgcn_mfma_f32_16x16x32_bf16(ao, hb, po, 0, 0, 0);
    }
    const unsigned tagT = (unsigned)TT;
    u64* ps = pout_buf + (size_t)2 * 384;
    st_agent(ps + oi,     (u64)pkv(po[0], tagT) | ((u64)pkv(po[1], tagT) << 32));
    st_agent(ps + oi + 1, (u64)pkv(po[2], tagT) | ((u64)pkv(po[3], tagT) << 32));
  }
  if (outduty && wv < 3) {
    {
      const unsigned otag = (unsigned)(TT - 1);
      const u64* ps = pout_buf + (size_t)((TT - 1) & 1) * 384;
      u64 w0, w1;
      int guard = RETRY_GUARD;
      for (;;) {
        w0 = ld_agent(ps + oi);
        w1 = ld_agent(ps + oi + 1);
        if (__all(tags2_ok(w0, w1, otag)) || --guard == 0) break;
        __builtin_amdgcn_s_sleep(1);
      }
      float pr[4] = { bfhi((unsigned)w0), bfhi((unsigned)(w0 >> 32)),
                      bfhi((unsigned)w1), bfhi((unsigned)(w1 >> 32)) };
#pragma unroll
      for (int r = 0; r < 4; ++r) {
        int o = wv * 16 + krow * 4 + r;
        if (o < NOUT)
          out[((size_t)(TT - 2) * BB + gb + bcol) * NOUT + o] = po_hold[r] + pr[r] + woutb[r];
      }
    }
    {
      f32x4 po = {0.f, 0.f, 0.f, 0.f};
#pragma unroll
      for (int kto = 0; kto < 8; ++kto) {
        int k0 = kto * 32 + krow * 8;
        bf16x8 hb = __builtin_bit_cast(bf16x8,
            *reinterpret_cast<const uint4*>(&h_lds[bcol * HALF + (k0 ^ sw)]));
        bf16x8 ao = __builtin_bit_cast(bf16x8,
            *reinterpret_cast<const uint4*>(&wout_lds[(wv * 8 + kto) * 512 + lane * 8]));
        po = __builtin_amdgcn_mfma_f32_16x16x32_bf16(ao, hb, po, 0, 0, 0);
      }
      const unsigned tagT = (unsigned)TT;
      const u64* ps = pout_buf + (size_t)2 * 384;
      u64 w0, w1;
      int guard = RETRY_GUARD;
      for (;;) {
        w0 = ld_agent(ps + oi);
        w1 = ld_agent(ps + oi + 1);
        if (__all(tags2_ok(w0, w1, tagT)) || --guard == 0) break;
        __builtin_amdgcn_s_sleep(1);
      }
      float pr[4] = { bfhi((unsigned)w0), bfhi((unsigned)(w0 >> 32)),
                      bfhi((unsigned)w1), bfhi((unsigned)(w1 >> 32)) };
#pragma unroll
      for (int r = 0; r < 4; ++r) {
        int o = wv * 16 + krow * 4 + r;
        if (o < NOUT)
          out[((size_t)(TT - 1) * BB + gb + bcol) * NOUT + o] = po[r] + pr[r] + woutb[r];
      }
    }
  }
}

extern "C" void kernel_launch(void* const* d_in, const int* in_sizes, int n_in,
                              void* d_out, int out_size, void* d_ws, size_t ws_size,
                              hipStream_t stream) {
  (void)in_sizes; (void)n_in; (void)out_size;
  const float* x      = (const float*)d_in[0];
  const float* noise  = (const float*)d_in[1];
  const float* Ws_w   = (const float*)d_in[2];
  const float* Ws_b   = (const float*)d_in[3];
  const float* Wr_w   = (const float*)d_in[4];
  const float* Wrec_w = (const float*)d_in[5];
  const float* Wrec_b = (const float*)d_in[6];
  const float* mask   = (const float*)d_in[7];
  const float* Wout_w = (const float*)d_in[8];
  const float* Wout_b = (const float*)d_in[9];
  unsigned char* ws   = (unsigned char*)d_ws;
  float* out          = (float*)d_out;

  pack_weights<<<(NFRAG_TOT * 64 + 255) / 256, 256, 0, stream>>>(
      Ws_w, Wr_w, Wrec_w, mask, Wout_w, (us*)ws);

  if (ws_size >= (size_t)SNEED) {
    us* pre = (us*)(ws + BPRE_OFF);
    precompute_pre<<<TT * 16, 512, 0, stream>>>(x, noise, Ws_b, Wrec_b, (us*)ws, pre);
    rnn_seq16<<<16, 512, 0, stream>>>(ws);
    out_gemm<<<TT * 16, 256, 0, stream>>>(pre, (us*)ws, Wout_b, out);
  } else {
    hipMemsetAsync(ws + PREC_OFF, 0, EXCH_BYTES, stream);
    rnn_fused<<<32, 512, 0, stream>>>(x, noise, Ws_b, Wrec_b, Wout_b, ws, out);
  }
}